// Round 9
// baseline (364.689 us; speedup 1.0000x reference)
//
#include <hip/hip_runtime.h>

#define NN 50000
#define NE 800000
#define D 128
#define NEG 0.2f

#define NBLK1 256        // pass-1 blocks
#define TILE1 3125       // NE / NBLK1 (exact)
#define NB2 196          // coarse buckets (dst>>8)
#define CAP2 8192        // max edges per coarse bucket
#define NT64 782         // ceil(NN/64) row tiles
#define ABLK 12500       // aggregate blocks (4 nodes each)

// setup kernel block ranges
#define SB_PREP 576              // 9 matrices x 64 blocks
#define SB_CONV 6250             // NN*D/4/256
#define SB_TOTAL (SB_PREP + SB_CONV + NBLK1)

typedef short bf8_t __attribute__((ext_vector_type(8)));   // 8 x bf16 (16 B)
typedef float f4_t __attribute__((ext_vector_type(4)));
typedef float f2_t __attribute__((ext_vector_type(2)));

__device__ __forceinline__ unsigned short f2bf(float f) {
  unsigned int u = __float_as_uint(f);
  return (unsigned short)((u + 0x7FFF + ((u >> 16) & 1)) >> 16);  // RNE
}
__device__ __forceinline__ float bf2f(unsigned int b) { return __uint_as_float(b << 16); }

__device__ __forceinline__ unsigned char f2fp8(float v) {
  int p = __builtin_amdgcn_cvt_pk_fp8_f32(v, v, 0, false);  // OCP e4m3 on gfx950
  return (unsigned char)(p & 0xFF);
}
template <bool HI>
__device__ __forceinline__ f2_t fp8pair(unsigned int w) {
  return __builtin_amdgcn_cvt_pk_f32_fp8((int)w, HI);  // HI is an immediate
}

__device__ __forceinline__ f4_t MF(bf8_t a, bf8_t b, f4_t c) {
  return __builtin_amdgcn_mfma_f32_16x16x32_bf16(a, b, c, 0, 0, 0);
}

// ---------------- GEMM building blocks (64-row tile, 4 waves, 16 rows/wave) ----------

__device__ __forceinline__ void stage_w(unsigned short* wbuf,
                                        const unsigned short* __restrict__ WT, int t) {
#pragma unroll
  for (int i = 0; i < 8; ++i) {
    int idx8 = t + i * 256;
    *(uint4*)(wbuf + idx8 * 8) = *(const uint4*)(WT + idx8 * 8);
  }
}

__device__ __forceinline__ void load_a16(const unsigned short* __restrict__ A,
                                         int base, int l15, int quad, bf8_t (&afr)[4]) {
  int r = base + l15;
  if (r >= NN) r = NN - 1;
  const unsigned short* p = A + (size_t)r * D + quad * 8;
#pragma unroll
  for (int kc = 0; kc < 4; ++kc) afr[kc] = *(const bf8_t*)(p + kc * 32);
}

// frag load from XOR-swizzled 64x128 LDS tile (rows local to block)
__device__ __forceinline__ void load_a16_swz(const unsigned short* hbuf,
                                             int wave, int l15, int quad, bf8_t (&afr)[4]) {
  int r = wave * 16 + l15;
#pragma unroll
  for (int kc = 0; kc < 4; ++kc) {
    int chunk = kc * 4 + quad;
    afr[kc] = *(const bf8_t*)(hbuf + r * D + ((chunk ^ (r & 7)) << 3));
  }
}

__device__ __forceinline__ void tile16(const unsigned short* wbuf, const bf8_t (&afr)[4],
                                       int l15, int quad, f4_t (&acc)[8]) {
#pragma unroll
  for (int kc = 0; kc < 4; ++kc)
#pragma unroll
    for (int nt = 0; nt < 8; ++nt) {
      bf8_t b = *(const bf8_t*)(wbuf + (nt * 16 + l15) * D + kc * 32 + quad * 8);
      acc[nt] = MF(afr[kc], b, acc[nt]);
    }
}

// epilogue: bf16 store to global
__device__ __forceinline__ void epi_bf(const f4_t (&acc)[8], const float* __restrict__ bias,
                                       unsigned short* __restrict__ C, int base,
                                       int l15, int quad, bool leaky) {
#pragma unroll
  for (int nt = 0; nt < 8; ++nt) {
    int col = nt * 16 + l15;
    float b = bias[col];
#pragma unroll
    for (int reg = 0; reg < 4; ++reg) {
      int row = base + quad * 4 + reg;
      if (row < NN) {
        float v = acc[nt][reg] + b;
        if (leaky) v = v >= 0.f ? v : NEG * v;
        C[(size_t)row * D + col] = f2bf(v);
      }
    }
  }
}

// epilogue: fp8 store to global
__device__ __forceinline__ void epi_fp8(const f4_t (&acc)[8], const float* __restrict__ bias,
                                        unsigned char* __restrict__ C, int base,
                                        int l15, int quad) {
#pragma unroll
  for (int nt = 0; nt < 8; ++nt) {
    int col = nt * 16 + l15;
    float b = bias[col];
#pragma unroll
    for (int reg = 0; reg < 4; ++reg) {
      int row = base + quad * 4 + reg;
      if (row < NN) C[(size_t)row * D + col] = f2fp8(acc[nt][reg] + b);
    }
  }
}

// ---------------- setup: weight prep + feats convert + coarse histogram --------------
__global__ __launch_bounds__(256) void setup(
    const float* __restrict__ Wq, const float* __restrict__ Wk,
    const float* __restrict__ Wr, const float* __restrict__ Wro,
    const float* __restrict__ feats, const int* __restrict__ dst,
    unsigned short* __restrict__ WT, unsigned short* __restrict__ x0,
    int* __restrict__ H) {
  __shared__ int cnt[NB2];
  const int b = blockIdx.x;
  const int t = threadIdx.x;
  if (b < SB_PREP) {
    const int m = b >> 6, xb = b & 63;
    const float* src;
    if (m < 2) src = Wq + m * D * D;
    else if (m < 4) src = Wk + (m - 2) * D * D;
    else if (m < 6) src = Wr + (m - 4) * D * D;
    else src = Wro + (m - 6) * D * D;
    const int n = xb * 2 + (t >> 7);
    const int k = t & 127;
    WT[(size_t)m * D * D + n * D + k] = f2bf(src[k * D + n]);
  } else if (b < SB_PREP + SB_CONV) {
    int i = ((b - SB_PREP) * 256 + t) * 4;
    float4 v = *(const float4*)(feats + i);
    ushort4 o = {f2bf(v.x), f2bf(v.y), f2bf(v.z), f2bf(v.w)};
    *(ushort4*)(x0 + i) = o;
  } else {
    const int blk = b - SB_PREP - SB_CONV;
    if (t < NB2) cnt[t] = 0;
    __syncthreads();
    const int beg = blk * TILE1, end = beg + TILE1;
    for (int i = beg + t; i < end; i += 256) atomicAdd(&cnt[dst[i] >> 8], 1);
    __syncthreads();
    if (t < NB2) H[t * NBLK1 + blk] = cnt[t];
  }
}

// ---------------- p1_scan: per-bin block computes its own base + row scan ------------
__global__ __launch_bounds__(256) void p1_scan(const int* __restrict__ H,
                                               int* __restrict__ gofs) {
  __shared__ int sd[256];
  __shared__ int wsum[4];
  const int bin = blockIdx.x;
  const int t = threadIdx.x;
  const int wave = t >> 6, lane = t & 63;
  int part = 0;
  for (int b2 = 0; b2 < bin; ++b2) part += H[b2 * NBLK1 + t];
  for (int off = 32; off; off >>= 1) part += __shfl_down(part, off, 64);
  if (lane == 0) wsum[wave] = part;
  __syncthreads();
  const int base = wsum[0] + wsum[1] + wsum[2] + wsum[3];
  int x = H[bin * NBLK1 + t];
  sd[t] = x;
  __syncthreads();
  int acc = x;
  for (int off = 1; off < 256; off <<= 1) {
    int y = (t >= off) ? sd[t - off] : 0;
    __syncthreads();
    acc += y;
    sd[t] = acc;
    __syncthreads();
  }
  gofs[bin * NBLK1 + t] = base + (acc - x);
}

__global__ __launch_bounds__(256) void p1_scatter(const int* __restrict__ src,
                                                  const int* __restrict__ dst,
                                                  const int* __restrict__ gofs,
                                                  unsigned int* __restrict__ ebuf) {
  __shared__ int lofs[NB2];
  const int t = threadIdx.x;
  const int blk = blockIdx.x;
  if (t < NB2) lofs[t] = gofs[t * NBLK1 + blk];
  __syncthreads();
  const int beg = blk * TILE1, end = beg + TILE1;
  for (int i = beg + t; i < end; i += 256) {
    unsigned int d = (unsigned int)dst[i];
    int pos = atomicAdd(&lofs[d >> 8], 1);
    ebuf[pos] = (unsigned int)src[i] | (d << 16);
  }
}

// ---------------- merged: p2 counting sort + layer-0 QK GEMM (hq bf16, hk fp8) -------
__global__ __launch_bounds__(256) void sort_qk0(
    const int* __restrict__ gofs, const unsigned int* __restrict__ ebuf,
    int* __restrict__ ssrc, int* __restrict__ rowptr, int* __restrict__ deg,
    const unsigned short* __restrict__ x0,
    const unsigned short* __restrict__ WTq, const float* __restrict__ bq_,
    const unsigned short* __restrict__ WTk, const float* __restrict__ bk_,
    unsigned short* __restrict__ hq, unsigned char* __restrict__ hk8) {
  __shared__ __align__(16) unsigned char smraw[35840];
  const int t = threadIdx.x;
  const int gx = blockIdx.x;
  if (gx < NB2) {
    int* cnt = (int*)smraw;
    int* fill = cnt + 256;
    int* sd = fill + 256;
    unsigned int* sorted = (unsigned int*)(sd + 256);
    const int b = gx;
    const int beg = gofs[b * NBLK1];
    const int end = (b + 1 < NB2) ? gofs[(b + 1) * NBLK1] : NE;
    const int n = end - beg;
    cnt[t] = 0;
    __syncthreads();
    for (int i = beg + t; i < end; i += 256)
      atomicAdd(&cnt[(ebuf[i] >> 16) & 255], 1);
    __syncthreads();
    int x = cnt[t];
    sd[t] = x;
    __syncthreads();
    int acc = x;
    for (int off = 1; off < 256; off <<= 1) {
      int y = (t >= off) ? sd[t - off] : 0;
      __syncthreads();
      acc += y;
      sd[t] = acc;
      __syncthreads();
    }
    const int excl = acc - x;
    fill[t] = excl;
    __syncthreads();
    for (int i = beg + t; i < end; i += 256) {
      unsigned int p = ebuf[i];
      int pos = atomicAdd(&fill[(p >> 16) & 255], 1);
      if (pos < CAP2) sorted[pos] = p;
    }
    __syncthreads();
    for (int i = t; i < n; i += 256) ssrc[beg + i] = (int)(sorted[i] & 0xFFFFu);
    const int node = (b << 8) + t;
    if (node < NN) {
      rowptr[node] = beg + excl;
      deg[node] = x;
    }
    if (b == 0 && t == 0) rowptr[NN] = NE;
  } else {
    unsigned short* wbuf = (unsigned short*)smraw;
    const int g = gx - NB2;
    const int sel = g & 1, tile = g >> 1;
    const int wave = t >> 6, lane = t & 63;
    const int l15 = lane & 15, quad = lane >> 4;
    const int base = tile * 64 + wave * 16;
    stage_w(wbuf, sel ? WTk : WTq, t);
    bf8_t afr[4];
    load_a16(x0, base, l15, quad, afr);
    __syncthreads();
    f4_t acc[8] = {};
    tile16(wbuf, afr, l15, quad, acc);
    if (sel) epi_fp8(acc, bk_, hk8, base, l15, quad);
    else epi_bf(acc, bq_, hq, base, l15, quad, false);
  }
}

// ---------------- aggregate (fp8 hk gather) + overlapped readout GEMM ----------------
#define PROC8(kb)                                                  \
  {                                                                \
    f2_t p; float m;                                               \
    p = fp8pair<false>(kb.x);                                      \
    m = q[0] + p.x; a[0] += m >= 0.f ? m : NEG * m;                \
    m = q[1] + p.y; a[1] += m >= 0.f ? m : NEG * m;                \
    p = fp8pair<true>(kb.x);                                       \
    m = q[2] + p.x; a[2] += m >= 0.f ? m : NEG * m;                \
    m = q[3] + p.y; a[3] += m >= 0.f ? m : NEG * m;                \
    p = fp8pair<false>(kb.y);                                      \
    m = q[4] + p.x; a[4] += m >= 0.f ? m : NEG * m;                \
    m = q[5] + p.y; a[5] += m >= 0.f ? m : NEG * m;                \
    p = fp8pair<true>(kb.y);                                       \
    m = q[6] + p.x; a[6] += m >= 0.f ? m : NEG * m;                \
    m = q[7] + p.y; a[7] += m >= 0.f ? m : NEG * m;                \
  }

template <bool ACCUM>
__global__ __launch_bounds__(256) void agg_ro(
    const int* __restrict__ rowptr, const int* __restrict__ ssrc,
    const int* __restrict__ deg,
    const unsigned short* __restrict__ hq, const unsigned char* __restrict__ hk8,
    unsigned short* __restrict__ ag,
    const unsigned short* __restrict__ Aro, const unsigned short* __restrict__ WTro,
    const float* __restrict__ bro_, float* __restrict__ out) {
  __shared__ unsigned short wbuf[D * D];
  const int t = threadIdx.x;
  const int gx = blockIdx.x;
  if (gx < ABLK) {
    const int wave = t >> 6, lane = t & 63;
    const int v = gx * 4 + wave;
    const int sub = lane & 15, grp = lane >> 4;
    const int beg = rowptr[v], end = rowptr[v + 1];

    uint4 qb = *(const uint4*)(hq + (size_t)v * D + sub * 8);
    float q[8];
    q[0] = bf2f(qb.x & 0xFFFFu); q[1] = bf2f(qb.x >> 16);
    q[2] = bf2f(qb.y & 0xFFFFu); q[3] = bf2f(qb.y >> 16);
    q[4] = bf2f(qb.z & 0xFFFFu); q[5] = bf2f(qb.z >> 16);
    q[6] = bf2f(qb.w & 0xFFFFu); q[7] = bf2f(qb.w >> 16);

    float a[8] = {0.f, 0.f, 0.f, 0.f, 0.f, 0.f, 0.f, 0.f};
    int e = beg + grp;
    for (; e + 4 < end; e += 8) {   // two streams -> 8 loads in flight per wave
      int s0 = ssrc[e];
      int s1 = ssrc[e + 4];
      uint2 k0 = *(const uint2*)(hk8 + (size_t)s0 * D + sub * 8);
      uint2 k1 = *(const uint2*)(hk8 + (size_t)s1 * D + sub * 8);
      PROC8(k0);
      PROC8(k1);
    }
    if (e < end) {
      int s0 = ssrc[e];
      uint2 k0 = *(const uint2*)(hk8 + (size_t)s0 * D + sub * 8);
      PROC8(k0);
    }
#pragma unroll
    for (int j = 0; j < 8; ++j) {
      a[j] += __shfl_xor(a[j], 16, 64);
      a[j] += __shfl_xor(a[j], 32, 64);
    }
    if (grp == 0) {
      float inv = 1.f / fmaxf((float)deg[v], 1.f);
      uint4 o;
      o.x = (unsigned int)f2bf(a[0] * inv) | ((unsigned int)f2bf(a[1] * inv) << 16);
      o.y = (unsigned int)f2bf(a[2] * inv) | ((unsigned int)f2bf(a[3] * inv) << 16);
      o.z = (unsigned int)f2bf(a[4] * inv) | ((unsigned int)f2bf(a[5] * inv) << 16);
      o.w = (unsigned int)f2bf(a[6] * inv) | ((unsigned int)f2bf(a[7] * inv) << 16);
      *(uint4*)(ag + (size_t)v * D + sub * 8) = o;
    }
  } else {
    // readout partial: out (+)= Aro @ WTro + bro_
    const int wave = t >> 6, lane = t & 63;
    const int l15 = lane & 15, quad = lane >> 4;
    const int base = (gx - ABLK) * 64 + wave * 16;
    stage_w(wbuf, WTro, t);
    bf8_t afr[4];
    load_a16(Aro, base, l15, quad, afr);
    __syncthreads();
    f4_t acc[8] = {};
    tile16(wbuf, afr, l15, quad, acc);
#pragma unroll
    for (int nt = 0; nt < 8; ++nt) {
      int col = nt * 16 + l15;
      float b = bro_[col];
#pragma unroll
      for (int reg = 0; reg < 4; ++reg) {
        int row = base + quad * 4 + reg;
        if (row < NN) {
          float v = acc[nt][reg] + b;
          float* p = out + (size_t)row * D + col;
          if (ACCUM) v += *p;
          *p = v;
        }
      }
    }
  }
}

// ---------------- r0+qk1: ag@Wr0 -> h1 (LDS+global); h1@Wq1 -> hq; h1@Wk1 -> hk8 -----
__global__ __launch_bounds__(256) void r0qk1(
    const unsigned short* __restrict__ ag,
    const unsigned short* __restrict__ WTr, const float* __restrict__ br_,
    const unsigned short* __restrict__ WTq, const float* __restrict__ bq_,
    const unsigned short* __restrict__ WTk, const float* __restrict__ bk_,
    unsigned short* __restrict__ h1, unsigned short* __restrict__ hq,
    unsigned char* __restrict__ hk8) {
  __shared__ unsigned short wbuf[D * D];
  __shared__ unsigned short hbuf[64 * D];
  const int t = threadIdx.x, wave = t >> 6, lane = t & 63;
  const int l15 = lane & 15, quad = lane >> 4;
  const int base = blockIdx.x * 64 + wave * 16;

  stage_w(wbuf, WTr, t);
  bf8_t afr[4];
  load_a16(ag, base, l15, quad, afr);
  __syncthreads();
  f4_t acc[8] = {};
  tile16(wbuf, afr, l15, quad, acc);

  // epilogue: h1 = leaky(acc + br) -> swizzled LDS + global
#pragma unroll
  for (int nt = 0; nt < 8; ++nt) {
    int col = nt * 16 + l15;
    float b = br_[col];
#pragma unroll
    for (int reg = 0; reg < 4; ++reg) {
      int rl = wave * 16 + quad * 4 + reg;
      float v = acc[nt][reg] + b;
      v = v >= 0.f ? v : NEG * v;
      unsigned short s = f2bf(v);
      hbuf[rl * D + (((col >> 3) ^ (rl & 7)) << 3) + (col & 7)] = s;
      int row = blockIdx.x * 64 + rl;
      if (row < NN) h1[(size_t)row * D + col] = s;
    }
  }
  __syncthreads();        // wbuf reads + hbuf writes complete
  stage_w(wbuf, WTq, t);
  __syncthreads();

  load_a16_swz(hbuf, wave, l15, quad, afr);
  f4_t acc2[8] = {};
  tile16(wbuf, afr, l15, quad, acc2);
  epi_bf(acc2, bq_, hq, base, l15, quad, false);
  __syncthreads();        // wbuf reads complete
  stage_w(wbuf, WTk, t);
  __syncthreads();

  f4_t acc3[8] = {};
  tile16(wbuf, afr, l15, quad, acc3);   // afr regs reused
  epi_fp8(acc3, bk_, hk8, base, l15, quad);
}

// ---------------- r1+ro2: ag@Wr1 -> h2 (LDS only); out += h2@Wro2 + bro2 -------------
__global__ __launch_bounds__(256) void r1ro2(
    const unsigned short* __restrict__ ag,
    const unsigned short* __restrict__ WTr, const float* __restrict__ br_,
    const unsigned short* __restrict__ WTro, const float* __restrict__ bro_,
    float* __restrict__ out) {
  __shared__ unsigned short wbuf[D * D];
  __shared__ unsigned short hbuf[64 * D];
  const int t = threadIdx.x, wave = t >> 6, lane = t & 63;
  const int l15 = lane & 15, quad = lane >> 4;
  const int base = blockIdx.x * 64 + wave * 16;

  stage_w(wbuf, WTr, t);
  bf8_t afr[4];
  load_a16(ag, base, l15, quad, afr);
  __syncthreads();
  f4_t acc[8] = {};
  tile16(wbuf, afr, l15, quad, acc);

#pragma unroll
  for (int nt = 0; nt < 8; ++nt) {
    int col = nt * 16 + l15;
    float b = br_[col];
#pragma unroll
    for (int reg = 0; reg < 4; ++reg) {
      int rl = wave * 16 + quad * 4 + reg;
      float v = acc[nt][reg] + b;
      v = v >= 0.f ? v : NEG * v;
      hbuf[rl * D + (((col >> 3) ^ (rl & 7)) << 3) + (col & 7)] = f2bf(v);
    }
  }
  __syncthreads();
  stage_w(wbuf, WTro, t);
  __syncthreads();

  load_a16_swz(hbuf, wave, l15, quad, afr);
  f4_t acc2[8] = {};
  tile16(wbuf, afr, l15, quad, acc2);
#pragma unroll
  for (int nt = 0; nt < 8; ++nt) {
    int col = nt * 16 + l15;
    float b = bro_[col];
#pragma unroll
    for (int reg = 0; reg < 4; ++reg) {
      int row = base + quad * 4 + reg;
      if (row < NN) {
        float* p = out + (size_t)row * D + col;
        *p = *p + acc2[nt][reg] + b;
      }
    }
  }
}

// ---------------- launch ----------------
extern "C" void kernel_launch(void* const* d_in, const int* in_sizes, int n_in,
                              void* d_out, int out_size, void* d_ws, size_t ws_size,
                              hipStream_t stream) {
  const float* feats = (const float*)d_in[0];
  const float* Wq = (const float*)d_in[1];
  const float* bq = (const float*)d_in[2];
  const float* Wk = (const float*)d_in[3];
  const float* bk = (const float*)d_in[4];
  const float* Wr = (const float*)d_in[5];
  const float* br = (const float*)d_in[6];
  const float* Wro = (const float*)d_in[7];
  const float* bro = (const float*)d_in[8];
  const int* src = (const int*)d_in[9];
  const int* dst = (const int*)d_in[10];
  float* out = (float*)d_out;

  size_t off = 0;
  char* base = (char*)d_ws;
  auto alloc = [&](size_t bytes) -> void* {
    void* p = base + off;
    off += (bytes + 255) & ~(size_t)255;
    return p;
  };
  int* H = (int*)alloc((size_t)NB2 * NBLK1 * 4);
  int* gofs = (int*)alloc((size_t)NB2 * NBLK1 * 4);
  unsigned int* ebuf = (unsigned int*)alloc((size_t)NE * 4);
  int* ssrc = (int*)alloc((size_t)NE * 4);
  int* rowptr = (int*)alloc((size_t)(NN + 1) * 4);
  int* deg = (int*)alloc((size_t)NN * 4);
  unsigned short* WT = (unsigned short*)alloc((size_t)9 * D * D * 2);
  unsigned short* x0 = (unsigned short*)alloc((size_t)NN * D * 2);
  unsigned short* hq = (unsigned short*)alloc((size_t)NN * D * 2);
  unsigned char* hk8 = (unsigned char*)alloc((size_t)NN * D);
  unsigned short* ag = (unsigned short*)alloc((size_t)NN * D * 2);
  unsigned short* h1 = (unsigned short*)alloc((size_t)NN * D * 2);

  const size_t WM = (size_t)D * D;

  // 1: weights + feats-convert + coarse hist
  setup<<<SB_TOTAL, 256, 0, stream>>>(Wq, Wk, Wr, Wro, feats, dst, WT, x0, H);
  // 2: hierarchical offsets
  p1_scan<<<NB2, 256, 0, stream>>>(H, gofs);
  // 3: bucket scatter
  p1_scatter<<<NBLK1, 256, 0, stream>>>(src, dst, gofs, ebuf);
  // 4: per-bucket sort || layer-0 QK GEMM (hq bf16, hk fp8)
  sort_qk0<<<NB2 + 2 * NT64, 256, 0, stream>>>(gofs, ebuf, ssrc, rowptr, deg,
                                               x0, WT + 0 * WM, bq, WT + 2 * WM, bk,
                                               hq, hk8);
  // 5: aggregate L0 || out = x0 @ Wro0 + bro0
  agg_ro<false><<<ABLK + NT64, 256, 0, stream>>>(rowptr, ssrc, deg, hq, hk8, ag,
                                                 x0, WT + 6 * WM, bro, out);
  // 6: h1 = leaky(ag@Wr0); hq1; hk1(fp8)
  r0qk1<<<NT64, 256, 0, stream>>>(ag, WT + 4 * WM, br,
                                  WT + 1 * WM, bq + D, WT + 3 * WM, bk + D,
                                  h1, hq, hk8);
  // 7: aggregate L1 || out += h1 @ Wro1 + bro1
  agg_ro<true><<<ABLK + NT64, 256, 0, stream>>>(rowptr, ssrc, deg, hq, hk8, ag,
                                                h1, WT + 7 * WM, bro + D, out);
  // 8: h2 = leaky(ag@Wr1) (LDS only); out += h2 @ Wro2 + bro2
  r1ro2<<<NT64, 256, 0, stream>>>(ag, WT + 5 * WM, br + D,
                                  WT + 8 * WM, bro + 2 * D, out);
}

// Round 10
// 324.939 us; speedup vs baseline: 1.1223x; 1.1223x over previous
//
#include <hip/hip_runtime.h>

#define NN 50000
#define NE 800000
#define D 128
#define NEG 0.2f

#define NBLK1 256        // pass-1 blocks
#define TILE1 3125       // NE / NBLK1 (exact)
#define NB2 196          // coarse buckets (dst>>8)
#define CAP2 8192        // max edges per coarse bucket
#define NT64 782         // ceil(NN/64) row tiles
#define ABLK 12500       // aggregate blocks (4 nodes each)

// setup kernel block ranges
#define SB_PREP 576              // 9 matrices x 64 blocks
#define SB_CONV 6250             // NN*D/4/256
#define SB_TOTAL (SB_PREP + SB_CONV + NBLK1)

typedef short bf8_t __attribute__((ext_vector_type(8)));   // 8 x bf16 (16 B)
typedef float f4_t __attribute__((ext_vector_type(4)));
typedef float f2_t __attribute__((ext_vector_type(2)));

__device__ __forceinline__ unsigned short f2bf(float f) {
  unsigned int u = __float_as_uint(f);
  return (unsigned short)((u + 0x7FFF + ((u >> 16) & 1)) >> 16);  // RNE
}
__device__ __forceinline__ float bf2f(unsigned int b) { return __uint_as_float(b << 16); }

__device__ __forceinline__ unsigned char f2fp8(float v) {
  int p = __builtin_amdgcn_cvt_pk_fp8_f32(v, v, 0, false);  // OCP e4m3 on gfx950
  return (unsigned char)(p & 0xFF);
}
template <bool HI>
__device__ __forceinline__ f2_t fp8pair(unsigned int w) {
  return __builtin_amdgcn_cvt_pk_f32_fp8((int)w, HI);  // HI immediate
}

__device__ __forceinline__ f4_t MF(bf8_t a, bf8_t b, f4_t c) {
  return __builtin_amdgcn_mfma_f32_16x16x32_bf16(a, b, c, 0, 0, 0);
}

// ---------------- GEMM building blocks (64-row tile, 4 waves, 16 rows/wave) ----------

__device__ __forceinline__ void stage_w(unsigned short* wbuf,
                                        const unsigned short* __restrict__ WT, int t) {
#pragma unroll
  for (int i = 0; i < 8; ++i) {
    int idx8 = t + i * 256;
    *(uint4*)(wbuf + idx8 * 8) = *(const uint4*)(WT + idx8 * 8);
  }
}

__device__ __forceinline__ void load_a16(const unsigned short* __restrict__ A,
                                         int base, int l15, int quad, bf8_t (&afr)[4]) {
  int r = base + l15;
  if (r >= NN) r = NN - 1;
  const unsigned short* p = A + (size_t)r * D + quad * 8;
#pragma unroll
  for (int kc = 0; kc < 4; ++kc) afr[kc] = *(const bf8_t*)(p + kc * 32);
}

// frag load from XOR-swizzled 64x128 LDS tile (rows local to block)
__device__ __forceinline__ void load_a16_swz(const unsigned short* hbuf,
                                             int wave, int l15, int quad, bf8_t (&afr)[4]) {
  int r = wave * 16 + l15;
#pragma unroll
  for (int kc = 0; kc < 4; ++kc) {
    int chunk = kc * 4 + quad;
    afr[kc] = *(const bf8_t*)(hbuf + r * D + ((chunk ^ (r & 7)) << 3));
  }
}

__device__ __forceinline__ void tile16(const unsigned short* wbuf, const bf8_t (&afr)[4],
                                       int l15, int quad, f4_t (&acc)[8]) {
#pragma unroll
  for (int kc = 0; kc < 4; ++kc)
#pragma unroll
    for (int nt = 0; nt < 8; ++nt) {
      bf8_t b = *(const bf8_t*)(wbuf + (nt * 16 + l15) * D + kc * 32 + quad * 8);
      acc[nt] = MF(afr[kc], b, acc[nt]);
    }
}

// epilogue: bf16 store to global
__device__ __forceinline__ void epi_bf(const f4_t (&acc)[8], const float* __restrict__ bias,
                                       unsigned short* __restrict__ C, int base,
                                       int l15, int quad) {
#pragma unroll
  for (int nt = 0; nt < 8; ++nt) {
    int col = nt * 16 + l15;
    float b = bias[col];
#pragma unroll
    for (int reg = 0; reg < 4; ++reg) {
      int row = base + quad * 4 + reg;
      if (row < NN) C[(size_t)row * D + col] = f2bf(acc[nt][reg] + b);
    }
  }
}

// epilogue: fp8 store to global
__device__ __forceinline__ void epi_fp8(const f4_t (&acc)[8], const float* __restrict__ bias,
                                        unsigned char* __restrict__ C, int base,
                                        int l15, int quad) {
#pragma unroll
  for (int nt = 0; nt < 8; ++nt) {
    int col = nt * 16 + l15;
    float b = bias[col];
#pragma unroll
    for (int reg = 0; reg < 4; ++reg) {
      int row = base + quad * 4 + reg;
      if (row < NN) C[(size_t)row * D + col] = f2fp8(acc[nt][reg] + b);
    }
  }
}

// epilogue: fp32 out, optional accumulate
template <bool ACCUM>
__device__ __forceinline__ void epi_f32(const f4_t (&acc)[8], const float* __restrict__ bias,
                                        float* __restrict__ out, int base,
                                        int l15, int quad) {
#pragma unroll
  for (int nt = 0; nt < 8; ++nt) {
    int col = nt * 16 + l15;
    float b = bias[col];
#pragma unroll
    for (int reg = 0; reg < 4; ++reg) {
      int row = base + quad * 4 + reg;
      if (row < NN) {
        float v = acc[nt][reg] + b;
        float* p = out + (size_t)row * D + col;
        if (ACCUM) v += *p;
        *p = v;
      }
    }
  }
}

// ---------------- setup: weight prep + feats convert + coarse histogram --------------
__global__ __launch_bounds__(256) void setup(
    const float* __restrict__ Wq, const float* __restrict__ Wk,
    const float* __restrict__ Wr, const float* __restrict__ Wro,
    const float* __restrict__ feats, const int* __restrict__ dst,
    unsigned short* __restrict__ WT, unsigned short* __restrict__ x0,
    int* __restrict__ H) {
  __shared__ int cnt[NB2];
  const int b = blockIdx.x;
  const int t = threadIdx.x;
  if (b < SB_PREP) {
    const int m = b >> 6, xb = b & 63;
    const float* src;
    if (m < 2) src = Wq + m * D * D;
    else if (m < 4) src = Wk + (m - 2) * D * D;
    else if (m < 6) src = Wr + (m - 4) * D * D;
    else src = Wro + (m - 6) * D * D;
    const int n = xb * 2 + (t >> 7);
    const int k = t & 127;
    WT[(size_t)m * D * D + n * D + k] = f2bf(src[k * D + n]);
  } else if (b < SB_PREP + SB_CONV) {
    int i = ((b - SB_PREP) * 256 + t) * 4;
    float4 v = *(const float4*)(feats + i);
    ushort4 o = {f2bf(v.x), f2bf(v.y), f2bf(v.z), f2bf(v.w)};
    *(ushort4*)(x0 + i) = o;
  } else {
    const int blk = b - SB_PREP - SB_CONV;
    if (t < NB2) cnt[t] = 0;
    __syncthreads();
    const int beg = blk * TILE1, end = beg + TILE1;
    for (int i = beg + t; i < end; i += 256) atomicAdd(&cnt[dst[i] >> 8], 1);
    __syncthreads();
    if (t < NB2) H[t * NBLK1 + blk] = cnt[t];
  }
}

// ---------------- p1_scan: per-bin block computes its own base + row scan ------------
__global__ __launch_bounds__(256) void p1_scan(const int* __restrict__ H,
                                               int* __restrict__ gofs) {
  __shared__ int sd[256];
  __shared__ int wsum[4];
  const int bin = blockIdx.x;
  const int t = threadIdx.x;
  const int wave = t >> 6, lane = t & 63;
  int part = 0;
  for (int b2 = 0; b2 < bin; ++b2) part += H[b2 * NBLK1 + t];
  for (int off = 32; off; off >>= 1) part += __shfl_down(part, off, 64);
  if (lane == 0) wsum[wave] = part;
  __syncthreads();
  const int base = wsum[0] + wsum[1] + wsum[2] + wsum[3];
  int x = H[bin * NBLK1 + t];
  sd[t] = x;
  __syncthreads();
  int acc = x;
  for (int off = 1; off < 256; off <<= 1) {
    int y = (t >= off) ? sd[t - off] : 0;
    __syncthreads();
    acc += y;
    sd[t] = acc;
    __syncthreads();
  }
  gofs[bin * NBLK1 + t] = base + (acc - x);
}

__global__ __launch_bounds__(256) void p1_scatter(const int* __restrict__ src,
                                                  const int* __restrict__ dst,
                                                  const int* __restrict__ gofs,
                                                  unsigned int* __restrict__ ebuf) {
  __shared__ int lofs[NB2];
  const int t = threadIdx.x;
  const int blk = blockIdx.x;
  if (t < NB2) lofs[t] = gofs[t * NBLK1 + blk];
  __syncthreads();
  const int beg = blk * TILE1, end = beg + TILE1;
  for (int i = beg + t; i < end; i += 256) {
    unsigned int d = (unsigned int)dst[i];
    int pos = atomicAdd(&lofs[d >> 8], 1);
    ebuf[pos] = (unsigned int)src[i] | (d << 16);
  }
}

// -------- merged: p2 sort (196) + QK0 GEMM (1564) + RO0 GEMM (782) -------------------
__global__ __launch_bounds__(256) void sort_qk0(
    const int* __restrict__ gofs, const unsigned int* __restrict__ ebuf,
    int* __restrict__ ssrc, int* __restrict__ rowptr, int* __restrict__ deg,
    const unsigned short* __restrict__ x0,
    const unsigned short* __restrict__ WTq, const float* __restrict__ bq_,
    const unsigned short* __restrict__ WTk, const float* __restrict__ bk_,
    const unsigned short* __restrict__ WTro, const float* __restrict__ bro_,
    unsigned short* __restrict__ hq, unsigned char* __restrict__ hk8,
    float* __restrict__ out) {
  __shared__ __align__(16) unsigned char smraw[35840];
  const int t = threadIdx.x;
  const int gx = blockIdx.x;
  if (gx < NB2) {
    int* cnt = (int*)smraw;
    int* fill = cnt + 256;
    int* sd = fill + 256;
    unsigned int* sorted = (unsigned int*)(sd + 256);
    const int b = gx;
    const int beg = gofs[b * NBLK1];
    const int end = (b + 1 < NB2) ? gofs[(b + 1) * NBLK1] : NE;
    const int n = end - beg;
    cnt[t] = 0;
    __syncthreads();
    for (int i = beg + t; i < end; i += 256)
      atomicAdd(&cnt[(ebuf[i] >> 16) & 255], 1);
    __syncthreads();
    int x = cnt[t];
    sd[t] = x;
    __syncthreads();
    int acc = x;
    for (int off = 1; off < 256; off <<= 1) {
      int y = (t >= off) ? sd[t - off] : 0;
      __syncthreads();
      acc += y;
      sd[t] = acc;
      __syncthreads();
    }
    const int excl = acc - x;
    fill[t] = excl;
    __syncthreads();
    for (int i = beg + t; i < end; i += 256) {
      unsigned int p = ebuf[i];
      int pos = atomicAdd(&fill[(p >> 16) & 255], 1);
      if (pos < CAP2) sorted[pos] = p;
    }
    __syncthreads();
    for (int i = t; i < n; i += 256) ssrc[beg + i] = (int)(sorted[i] & 0xFFFFu);
    const int node = (b << 8) + t;
    if (node < NN) {
      rowptr[node] = beg + excl;
      deg[node] = x;
    }
    if (b == 0 && t == 0) rowptr[NN] = NE;
  } else {
    unsigned short* wbuf = (unsigned short*)smraw;
    const int g = gx - NB2;
    const int wave = t >> 6, lane = t & 63;
    const int l15 = lane & 15, quad = lane >> 4;
    if (g < 2 * NT64) {
      const int sel = g & 1, tile = g >> 1;
      const int base = tile * 64 + wave * 16;
      stage_w(wbuf, sel ? WTk : WTq, t);
      bf8_t afr[4];
      load_a16(x0, base, l15, quad, afr);
      __syncthreads();
      f4_t acc[8] = {};
      tile16(wbuf, afr, l15, quad, acc);
      if (sel) epi_fp8(acc, bk_, hk8, base, l15, quad);
      else epi_bf(acc, bq_, hq, base, l15, quad);
    } else {
      const int base = (g - 2 * NT64) * 64 + wave * 16;
      stage_w(wbuf, WTro, t);
      bf8_t afr[4];
      load_a16(x0, base, l15, quad, afr);
      __syncthreads();
      f4_t acc[8] = {};
      tile16(wbuf, afr, l15, quad, acc);
      epi_f32<false>(acc, bro_, out, base, l15, quad);
    }
  }
}

// ---------------- aggregation: STANDALONE, zero LDS, fp8 gather ----------------------
#define PROC8(kb)                                                  \
  {                                                                \
    f2_t p; float m;                                               \
    p = fp8pair<false>(kb.x);                                      \
    m = q[0] + p.x; a[0] += m >= 0.f ? m : NEG * m;                \
    m = q[1] + p.y; a[1] += m >= 0.f ? m : NEG * m;                \
    p = fp8pair<true>(kb.x);                                       \
    m = q[2] + p.x; a[2] += m >= 0.f ? m : NEG * m;                \
    m = q[3] + p.y; a[3] += m >= 0.f ? m : NEG * m;                \
    p = fp8pair<false>(kb.y);                                      \
    m = q[4] + p.x; a[4] += m >= 0.f ? m : NEG * m;                \
    m = q[5] + p.y; a[5] += m >= 0.f ? m : NEG * m;                \
    p = fp8pair<true>(kb.y);                                       \
    m = q[6] + p.x; a[6] += m >= 0.f ? m : NEG * m;                \
    m = q[7] + p.y; a[7] += m >= 0.f ? m : NEG * m;                \
  }

__global__ __launch_bounds__(256) void aggregate(
    const int* __restrict__ rowptr, const int* __restrict__ ssrc,
    const int* __restrict__ deg,
    const unsigned short* __restrict__ hq, const unsigned char* __restrict__ hk8,
    unsigned short* __restrict__ ag) {
  const int wave = threadIdx.x >> 6, lane = threadIdx.x & 63;
  const int v = blockIdx.x * 4 + wave;
  if (v >= NN) return;
  const int sub = lane & 15, grp = lane >> 4;
  const int beg = rowptr[v], end = rowptr[v + 1];

  uint4 qb = *(const uint4*)(hq + (size_t)v * D + sub * 8);
  float q[8];
  q[0] = bf2f(qb.x & 0xFFFFu); q[1] = bf2f(qb.x >> 16);
  q[2] = bf2f(qb.y & 0xFFFFu); q[3] = bf2f(qb.y >> 16);
  q[4] = bf2f(qb.z & 0xFFFFu); q[5] = bf2f(qb.z >> 16);
  q[6] = bf2f(qb.w & 0xFFFFu); q[7] = bf2f(qb.w >> 16);

  float a[8] = {0.f, 0.f, 0.f, 0.f, 0.f, 0.f, 0.f, 0.f};
  int e = beg + grp;
  for (; e + 4 < end; e += 8) {   // two streams -> 8 loads in flight per wave
    int s0 = ssrc[e];
    int s1 = ssrc[e + 4];
    uint2 k0 = *(const uint2*)(hk8 + (size_t)s0 * D + sub * 8);
    uint2 k1 = *(const uint2*)(hk8 + (size_t)s1 * D + sub * 8);
    PROC8(k0);
    PROC8(k1);
  }
  if (e < end) {
    int s0 = ssrc[e];
    uint2 k0 = *(const uint2*)(hk8 + (size_t)s0 * D + sub * 8);
    PROC8(k0);
  }
#pragma unroll
  for (int j = 0; j < 8; ++j) {
    a[j] += __shfl_xor(a[j], 16, 64);
    a[j] += __shfl_xor(a[j], 32, 64);
  }
  if (grp == 0) {
    float inv = 1.f / fmaxf((float)deg[v], 1.f);
    uint4 o;
    o.x = (unsigned int)f2bf(a[0] * inv) | ((unsigned int)f2bf(a[1] * inv) << 16);
    o.y = (unsigned int)f2bf(a[2] * inv) | ((unsigned int)f2bf(a[3] * inv) << 16);
    o.z = (unsigned int)f2bf(a[4] * inv) | ((unsigned int)f2bf(a[5] * inv) << 16);
    o.w = (unsigned int)f2bf(a[6] * inv) | ((unsigned int)f2bf(a[7] * inv) << 16);
    *(uint4*)(ag + (size_t)v * D + sub * 8) = o;
  }
}

// ------ r0qk1ro1: ag@Wr0 -> h1 (LDS only); h1@Wq1 -> hq; h1@Wk1 -> hk8;
//        out += h1@Wro1 + bro1.  h1 NEVER touches HBM. ----------------------------
__global__ __launch_bounds__(256) void r0qk1(
    const unsigned short* __restrict__ ag,
    const unsigned short* __restrict__ WTr, const float* __restrict__ br_,
    const unsigned short* __restrict__ WTq, const float* __restrict__ bq_,
    const unsigned short* __restrict__ WTk, const float* __restrict__ bk_,
    const unsigned short* __restrict__ WTro, const float* __restrict__ bro_,
    unsigned short* __restrict__ hq, unsigned char* __restrict__ hk8,
    float* __restrict__ out) {
  __shared__ unsigned short wbuf[D * D];
  __shared__ unsigned short hbuf[64 * D];
  const int t = threadIdx.x, wave = t >> 6, lane = t & 63;
  const int l15 = lane & 15, quad = lane >> 4;
  const int base = blockIdx.x * 64 + wave * 16;

  // P1: ag @ Wr0
  stage_w(wbuf, WTr, t);
  bf8_t afr[4];
  load_a16(ag, base, l15, quad, afr);
  __syncthreads();
  f4_t acc[8] = {};
  tile16(wbuf, afr, l15, quad, acc);

  // h1 = leaky(acc + br) -> swizzled LDS only
#pragma unroll
  for (int nt = 0; nt < 8; ++nt) {
    int col = nt * 16 + l15;
    float b = br_[col];
#pragma unroll
    for (int reg = 0; reg < 4; ++reg) {
      int rl = wave * 16 + quad * 4 + reg;
      float v = acc[nt][reg] + b;
      v = v >= 0.f ? v : NEG * v;
      hbuf[rl * D + (((col >> 3) ^ (rl & 7)) << 3) + (col & 7)] = f2bf(v);
    }
  }
  __syncthreads();        // wbuf reads + hbuf writes complete

  // P2: h1 @ Wq1 -> hq (bf16)
  stage_w(wbuf, WTq, t);
  __syncthreads();
  load_a16_swz(hbuf, wave, l15, quad, afr);   // h1 frags stay in regs from here
  f4_t acc2[8] = {};
  tile16(wbuf, afr, l15, quad, acc2);
  epi_bf(acc2, bq_, hq, base, l15, quad);
  __syncthreads();

  // P3: h1 @ Wk1 -> hk8 (fp8)
  stage_w(wbuf, WTk, t);
  __syncthreads();
  f4_t acc3[8] = {};
  tile16(wbuf, afr, l15, quad, acc3);
  epi_fp8(acc3, bk_, hk8, base, l15, quad);
  __syncthreads();

  // P4: out += h1 @ Wro1 + bro1
  stage_w(wbuf, WTro, t);
  __syncthreads();
  f4_t acc4[8] = {};
  tile16(wbuf, afr, l15, quad, acc4);
  epi_f32<true>(acc4, bro_, out, base, l15, quad);
}

// ---------------- r1ro2: ag@Wr1 -> h2 (LDS only); out += h2@Wro2 + bro2 --------------
__global__ __launch_bounds__(256) void r1ro2(
    const unsigned short* __restrict__ ag,
    const unsigned short* __restrict__ WTr, const float* __restrict__ br_,
    const unsigned short* __restrict__ WTro, const float* __restrict__ bro_,
    float* __restrict__ out) {
  __shared__ unsigned short wbuf[D * D];
  __shared__ unsigned short hbuf[64 * D];
  const int t = threadIdx.x, wave = t >> 6, lane = t & 63;
  const int l15 = lane & 15, quad = lane >> 4;
  const int base = blockIdx.x * 64 + wave * 16;

  stage_w(wbuf, WTr, t);
  bf8_t afr[4];
  load_a16(ag, base, l15, quad, afr);
  __syncthreads();
  f4_t acc[8] = {};
  tile16(wbuf, afr, l15, quad, acc);

#pragma unroll
  for (int nt = 0; nt < 8; ++nt) {
    int col = nt * 16 + l15;
    float b = br_[col];
#pragma unroll
    for (int reg = 0; reg < 4; ++reg) {
      int rl = wave * 16 + quad * 4 + reg;
      float v = acc[nt][reg] + b;
      v = v >= 0.f ? v : NEG * v;
      hbuf[rl * D + (((col >> 3) ^ (rl & 7)) << 3) + (col & 7)] = f2bf(v);
    }
  }
  __syncthreads();
  stage_w(wbuf, WTro, t);
  __syncthreads();

  load_a16_swz(hbuf, wave, l15, quad, afr);
  f4_t acc2[8] = {};
  tile16(wbuf, afr, l15, quad, acc2);
  epi_f32<true>(acc2, bro_, out, base, l15, quad);
}

// ---------------- launch ----------------
extern "C" void kernel_launch(void* const* d_in, const int* in_sizes, int n_in,
                              void* d_out, int out_size, void* d_ws, size_t ws_size,
                              hipStream_t stream) {
  const float* feats = (const float*)d_in[0];
  const float* Wq = (const float*)d_in[1];
  const float* bq = (const float*)d_in[2];
  const float* Wk = (const float*)d_in[3];
  const float* bk = (const float*)d_in[4];
  const float* Wr = (const float*)d_in[5];
  const float* br = (const float*)d_in[6];
  const float* Wro = (const float*)d_in[7];
  const float* bro = (const float*)d_in[8];
  const int* src = (const int*)d_in[9];
  const int* dst = (const int*)d_in[10];
  float* out = (float*)d_out;

  size_t off = 0;
  char* base = (char*)d_ws;
  auto alloc = [&](size_t bytes) -> void* {
    void* p = base + off;
    off += (bytes + 255) & ~(size_t)255;
    return p;
  };
  int* H = (int*)alloc((size_t)NB2 * NBLK1 * 4);
  int* gofs = (int*)alloc((size_t)NB2 * NBLK1 * 4);
  unsigned int* ebuf = (unsigned int*)alloc((size_t)NE * 4);
  int* ssrc = (int*)alloc((size_t)NE * 4);
  int* rowptr = (int*)alloc((size_t)(NN + 1) * 4);
  int* deg = (int*)alloc((size_t)NN * 4);
  unsigned short* WT = (unsigned short*)alloc((size_t)9 * D * D * 2);
  unsigned short* x0 = (unsigned short*)alloc((size_t)NN * D * 2);
  unsigned short* hq = (unsigned short*)alloc((size_t)NN * D * 2);
  unsigned char* hk8 = (unsigned char*)alloc((size_t)NN * D);
  unsigned short* ag = (unsigned short*)alloc((size_t)NN * D * 2);

  const size_t WM = (size_t)D * D;

  // 1: weights + feats-convert + coarse hist
  setup<<<SB_TOTAL, 256, 0, stream>>>(Wq, Wk, Wr, Wro, feats, dst, WT, x0, H);
  // 2: hierarchical offsets
  p1_scan<<<NB2, 256, 0, stream>>>(H, gofs);
  // 3: bucket scatter
  p1_scatter<<<NBLK1, 256, 0, stream>>>(src, dst, gofs, ebuf);
  // 4: per-bucket sort || QK0 GEMM || RO0 GEMM (out = x0@Wro0 + bro0)
  sort_qk0<<<NB2 + 3 * NT64, 256, 0, stream>>>(gofs, ebuf, ssrc, rowptr, deg,
                                               x0, WT + 0 * WM, bq, WT + 2 * WM, bk,
                                               WT + 6 * WM, bro, hq, hk8, out);
  // 5: aggregate L0 (standalone, zero LDS)
  aggregate<<<ABLK, 256, 0, stream>>>(rowptr, ssrc, deg, hq, hk8, ag);
  // 6: h1 = leaky(ag@Wr0) (LDS only); hq1; hk1(fp8); out += h1@Wro1 + bro1
  r0qk1<<<NT64, 256, 0, stream>>>(ag, WT + 4 * WM, br,
                                  WT + 1 * WM, bq + D, WT + 3 * WM, bk + D,
                                  WT + 7 * WM, bro + D, hq, hk8, out);
  // 7: aggregate L1 (standalone)
  aggregate<<<ABLK, 256, 0, stream>>>(rowptr, ssrc, deg, hq, hk8, ag);
  // 8: h2 = leaky(ag@Wr1) (LDS only); out += h2@Wro2 + bro2
  r1ro2<<<NT64, 256, 0, stream>>>(ag, WT + 5 * WM, br + D,
                                  WT + 8 * WM, bro + 2 * D, out);
}

// Round 11
// 320.373 us; speedup vs baseline: 1.1383x; 1.0143x over previous
//
#include <hip/hip_runtime.h>

#define NN 50000
#define NE 800000
#define D 128
#define NEG 0.2f

#define NBLK1 256        // pass-1 blocks
#define TILE1 3125       // NE / NBLK1 (exact)
#define NB2 196          // coarse buckets (dst>>8)
#define CAP2 8192        // max edges per coarse bucket
#define NT64 782         // ceil(NN/64) row tiles
#define ABLK 12500       // aggregate blocks (4 nodes each)

// setup kernel block ranges
#define SB_PREP 576              // 9 matrices x 64 blocks
#define SB_CONV 6250             // NN*D/4/256
#define SB_TOTAL (SB_PREP + SB_CONV + NBLK1)

typedef short bf8_t __attribute__((ext_vector_type(8)));   // 8 x bf16 (16 B)
typedef float f4_t __attribute__((ext_vector_type(4)));
typedef float f2_t __attribute__((ext_vector_type(2)));

__device__ __forceinline__ unsigned short f2bf(float f) {
  unsigned int u = __float_as_uint(f);
  return (unsigned short)((u + 0x7FFF + ((u >> 16) & 1)) >> 16);  // RNE
}
__device__ __forceinline__ float bf2f(unsigned int b) { return __uint_as_float(b << 16); }

__device__ __forceinline__ unsigned char f2fp8(float v) {
  int p = __builtin_amdgcn_cvt_pk_fp8_f32(v, v, 0, false);  // OCP e4m3 on gfx950
  return (unsigned char)(p & 0xFF);
}
template <bool HI>
__device__ __forceinline__ f2_t fp8pair(unsigned int w) {
  return __builtin_amdgcn_cvt_pk_f32_fp8((int)w, HI);  // HI immediate
}

__device__ __forceinline__ f4_t MF(bf8_t a, bf8_t b, f4_t c) {
  return __builtin_amdgcn_mfma_f32_16x16x32_bf16(a, b, c, 0, 0, 0);
}

// ---------------- GEMM building blocks (64-row tile, 4 waves, 16 rows/wave) ----------

__device__ __forceinline__ void stage_w(unsigned short* wbuf,
                                        const unsigned short* __restrict__ WT, int t) {
#pragma unroll
  for (int i = 0; i < 8; ++i) {
    int idx8 = t + i * 256;
    *(uint4*)(wbuf + idx8 * 8) = *(const uint4*)(WT + idx8 * 8);
  }
}

__device__ __forceinline__ void load_a16(const unsigned short* __restrict__ A,
                                         int base, int l15, int quad, bf8_t (&afr)[4]) {
  int r = base + l15;
  if (r >= NN) r = NN - 1;
  const unsigned short* p = A + (size_t)r * D + quad * 8;
#pragma unroll
  for (int kc = 0; kc < 4; ++kc) afr[kc] = *(const bf8_t*)(p + kc * 32);
}

__device__ __forceinline__ void tile16(const unsigned short* wbuf, const bf8_t (&afr)[4],
                                       int l15, int quad, f4_t (&acc)[8]) {
#pragma unroll
  for (int kc = 0; kc < 4; ++kc)
#pragma unroll
    for (int nt = 0; nt < 8; ++nt) {
      bf8_t b = *(const bf8_t*)(wbuf + (nt * 16 + l15) * D + kc * 32 + quad * 8);
      acc[nt] = MF(afr[kc], b, acc[nt]);
    }
}

// epilogue: bf16 store to global (optional leaky)
template <bool LEAKY>
__device__ __forceinline__ void epi_bf(const f4_t (&acc)[8], const float* __restrict__ bias,
                                       unsigned short* __restrict__ C, int base,
                                       int l15, int quad) {
#pragma unroll
  for (int nt = 0; nt < 8; ++nt) {
    int col = nt * 16 + l15;
    float b = bias[col];
#pragma unroll
    for (int reg = 0; reg < 4; ++reg) {
      int row = base + quad * 4 + reg;
      if (row < NN) {
        float v = acc[nt][reg] + b;
        if (LEAKY) v = v >= 0.f ? v : NEG * v;
        C[(size_t)row * D + col] = f2bf(v);
      }
    }
  }
}

// epilogue: fp8 store to global
__device__ __forceinline__ void epi_fp8(const f4_t (&acc)[8], const float* __restrict__ bias,
                                        unsigned char* __restrict__ C, int base,
                                        int l15, int quad) {
#pragma unroll
  for (int nt = 0; nt < 8; ++nt) {
    int col = nt * 16 + l15;
    float b = bias[col];
#pragma unroll
    for (int reg = 0; reg < 4; ++reg) {
      int row = base + quad * 4 + reg;
      if (row < NN) C[(size_t)row * D + col] = f2fp8(acc[nt][reg] + b);
    }
  }
}

// epilogue: fp32 out, optional accumulate
template <bool ACCUM>
__device__ __forceinline__ void epi_f32(const f4_t (&acc)[8], const float* __restrict__ bias,
                                        float* __restrict__ out, int base,
                                        int l15, int quad) {
#pragma unroll
  for (int nt = 0; nt < 8; ++nt) {
    int col = nt * 16 + l15;
    float b = bias[col];
#pragma unroll
    for (int reg = 0; reg < 4; ++reg) {
      int row = base + quad * 4 + reg;
      if (row < NN) {
        float v = acc[nt][reg] + b;
        float* p = out + (size_t)row * D + col;
        if (ACCUM) v += *p;
        *p = v;
      }
    }
  }
}

// ---------------- setup: weight prep + feats convert + coarse histogram --------------
__global__ __launch_bounds__(256) void setup(
    const float* __restrict__ Wq, const float* __restrict__ Wk,
    const float* __restrict__ Wr, const float* __restrict__ Wro,
    const float* __restrict__ feats, const int* __restrict__ dst,
    unsigned short* __restrict__ WT, unsigned short* __restrict__ x0,
    int* __restrict__ H) {
  __shared__ int cnt[NB2];
  const int b = blockIdx.x;
  const int t = threadIdx.x;
  if (b < SB_PREP) {
    const int m = b >> 6, xb = b & 63;
    const float* src;
    if (m < 2) src = Wq + m * D * D;
    else if (m < 4) src = Wk + (m - 2) * D * D;
    else if (m < 6) src = Wr + (m - 4) * D * D;
    else src = Wro + (m - 6) * D * D;
    const int n = xb * 2 + (t >> 7);
    const int k = t & 127;
    WT[(size_t)m * D * D + n * D + k] = f2bf(src[k * D + n]);
  } else if (b < SB_PREP + SB_CONV) {
    int i = ((b - SB_PREP) * 256 + t) * 4;
    float4 v = *(const float4*)(feats + i);
    ushort4 o = {f2bf(v.x), f2bf(v.y), f2bf(v.z), f2bf(v.w)};
    *(ushort4*)(x0 + i) = o;
  } else {
    const int blk = b - SB_PREP - SB_CONV;
    if (t < NB2) cnt[t] = 0;
    __syncthreads();
    const int beg = blk * TILE1, end = beg + TILE1;
    for (int i = beg + t; i < end; i += 256) atomicAdd(&cnt[dst[i] >> 8], 1);
    __syncthreads();
    if (t < NB2) H[t * NBLK1 + blk] = cnt[t];
  }
}

// ---------------- p1_scan: per-bin block computes its own base + row scan ------------
__global__ __launch_bounds__(256) void p1_scan(const int* __restrict__ H,
                                               int* __restrict__ gofs) {
  __shared__ int sd[256];
  __shared__ int wsum[4];
  const int bin = blockIdx.x;
  const int t = threadIdx.x;
  const int wave = t >> 6, lane = t & 63;
  int part = 0;
  for (int b2 = 0; b2 < bin; ++b2) part += H[b2 * NBLK1 + t];
  for (int off = 32; off; off >>= 1) part += __shfl_down(part, off, 64);
  if (lane == 0) wsum[wave] = part;
  __syncthreads();
  const int base = wsum[0] + wsum[1] + wsum[2] + wsum[3];
  int x = H[bin * NBLK1 + t];
  sd[t] = x;
  __syncthreads();
  int acc = x;
  for (int off = 1; off < 256; off <<= 1) {
    int y = (t >= off) ? sd[t - off] : 0;
    __syncthreads();
    acc += y;
    sd[t] = acc;
    __syncthreads();
  }
  gofs[bin * NBLK1 + t] = base + (acc - x);
}

__global__ __launch_bounds__(256) void p1_scatter(const int* __restrict__ src,
                                                  const int* __restrict__ dst,
                                                  const int* __restrict__ gofs,
                                                  unsigned int* __restrict__ ebuf) {
  __shared__ int lofs[NB2];
  const int t = threadIdx.x;
  const int blk = blockIdx.x;
  if (t < NB2) lofs[t] = gofs[t * NBLK1 + blk];
  __syncthreads();
  const int beg = blk * TILE1, end = beg + TILE1;
  for (int i = beg + t; i < end; i += 256) {
    unsigned int d = (unsigned int)dst[i];
    int pos = atomicAdd(&lofs[d >> 8], 1);
    ebuf[pos] = (unsigned int)src[i] | (d << 16);
  }
}

// -------- merged: p2 sort (196) + QK0 GEMM (1564) + RO0 GEMM (782) -------------------
__global__ __launch_bounds__(256) void sort_qk0(
    const int* __restrict__ gofs, const unsigned int* __restrict__ ebuf,
    int* __restrict__ ssrc, int* __restrict__ rowptr, int* __restrict__ deg,
    const unsigned short* __restrict__ x0,
    const unsigned short* __restrict__ WTq, const float* __restrict__ bq_,
    const unsigned short* __restrict__ WTk, const float* __restrict__ bk_,
    const unsigned short* __restrict__ WTro, const float* __restrict__ bro_,
    unsigned short* __restrict__ hq, unsigned char* __restrict__ hk8,
    float* __restrict__ out) {
  __shared__ __align__(16) unsigned char smraw[35840];
  const int t = threadIdx.x;
  const int gx = blockIdx.x;
  if (gx < NB2) {
    int* cnt = (int*)smraw;
    int* fill = cnt + 256;
    int* sd = fill + 256;
    unsigned int* sorted = (unsigned int*)(sd + 256);
    const int b = gx;
    const int beg = gofs[b * NBLK1];
    const int end = (b + 1 < NB2) ? gofs[(b + 1) * NBLK1] : NE;
    const int n = end - beg;
    cnt[t] = 0;
    __syncthreads();
    for (int i = beg + t; i < end; i += 256)
      atomicAdd(&cnt[(ebuf[i] >> 16) & 255], 1);
    __syncthreads();
    int x = cnt[t];
    sd[t] = x;
    __syncthreads();
    int acc = x;
    for (int off = 1; off < 256; off <<= 1) {
      int y = (t >= off) ? sd[t - off] : 0;
      __syncthreads();
      acc += y;
      sd[t] = acc;
      __syncthreads();
    }
    const int excl = acc - x;
    fill[t] = excl;
    __syncthreads();
    for (int i = beg + t; i < end; i += 256) {
      unsigned int p = ebuf[i];
      int pos = atomicAdd(&fill[(p >> 16) & 255], 1);
      if (pos < CAP2) sorted[pos] = p;
    }
    __syncthreads();
    for (int i = t; i < n; i += 256) ssrc[beg + i] = (int)(sorted[i] & 0xFFFFu);
    const int node = (b << 8) + t;
    if (node < NN) {
      rowptr[node] = beg + excl;
      deg[node] = x;
    }
    if (b == 0 && t == 0) rowptr[NN] = NE;
  } else {
    unsigned short* wbuf = (unsigned short*)smraw;
    const int g = gx - NB2;
    const int wave = t >> 6, lane = t & 63;
    const int l15 = lane & 15, quad = lane >> 4;
    if (g < 2 * NT64) {
      const int sel = g & 1, tile = g >> 1;
      const int base = tile * 64 + wave * 16;
      stage_w(wbuf, sel ? WTk : WTq, t);
      bf8_t afr[4];
      load_a16(x0, base, l15, quad, afr);
      __syncthreads();
      f4_t acc[8] = {};
      tile16(wbuf, afr, l15, quad, acc);
      if (sel) epi_fp8(acc, bk_, hk8, base, l15, quad);
      else epi_bf<false>(acc, bq_, hq, base, l15, quad);
    } else {
      const int base = (g - 2 * NT64) * 64 + wave * 16;
      stage_w(wbuf, WTro, t);
      bf8_t afr[4];
      load_a16(x0, base, l15, quad, afr);
      __syncthreads();
      f4_t acc[8] = {};
      tile16(wbuf, afr, l15, quad, acc);
      epi_f32<false>(acc, bro_, out, base, l15, quad);
    }
  }
}

// ---------------- aggregation: STANDALONE, zero LDS, fp8 gather ----------------------
#define PROC8(kb)                                                  \
  {                                                                \
    f2_t p; float m;                                               \
    p = fp8pair<false>(kb.x);                                      \
    m = q[0] + p.x; a[0] += m >= 0.f ? m : NEG * m;                \
    m = q[1] + p.y; a[1] += m >= 0.f ? m : NEG * m;                \
    p = fp8pair<true>(kb.x);                                       \
    m = q[2] + p.x; a[2] += m >= 0.f ? m : NEG * m;                \
    m = q[3] + p.y; a[3] += m >= 0.f ? m : NEG * m;                \
    p = fp8pair<false>(kb.y);                                      \
    m = q[4] + p.x; a[4] += m >= 0.f ? m : NEG * m;                \
    m = q[5] + p.y; a[5] += m >= 0.f ? m : NEG * m;                \
    p = fp8pair<true>(kb.y);                                       \
    m = q[6] + p.x; a[6] += m >= 0.f ? m : NEG * m;                \
    m = q[7] + p.y; a[7] += m >= 0.f ? m : NEG * m;                \
  }

__global__ __launch_bounds__(256) void aggregate(
    const int* __restrict__ rowptr, const int* __restrict__ ssrc,
    const int* __restrict__ deg,
    const unsigned short* __restrict__ hq, const unsigned char* __restrict__ hk8,
    unsigned short* __restrict__ ag) {
  const int wave = threadIdx.x >> 6, lane = threadIdx.x & 63;
  const int v = blockIdx.x * 4 + wave;
  if (v >= NN) return;
  const int sub = lane & 15, grp = lane >> 4;
  const int beg = rowptr[v], end = rowptr[v + 1];

  uint4 qb = *(const uint4*)(hq + (size_t)v * D + sub * 8);
  float q[8];
  q[0] = bf2f(qb.x & 0xFFFFu); q[1] = bf2f(qb.x >> 16);
  q[2] = bf2f(qb.y & 0xFFFFu); q[3] = bf2f(qb.y >> 16);
  q[4] = bf2f(qb.z & 0xFFFFu); q[5] = bf2f(qb.z >> 16);
  q[6] = bf2f(qb.w & 0xFFFFu); q[7] = bf2f(qb.w >> 16);

  float a[8] = {0.f, 0.f, 0.f, 0.f, 0.f, 0.f, 0.f, 0.f};
  int e = beg + grp;
  for (; e + 4 < end; e += 8) {   // two streams -> 8 loads in flight per wave
    int s0 = ssrc[e];
    int s1 = ssrc[e + 4];
    uint2 k0 = *(const uint2*)(hk8 + (size_t)s0 * D + sub * 8);
    uint2 k1 = *(const uint2*)(hk8 + (size_t)s1 * D + sub * 8);
    PROC8(k0);
    PROC8(k1);
  }
  if (e < end) {
    int s0 = ssrc[e];
    uint2 k0 = *(const uint2*)(hk8 + (size_t)s0 * D + sub * 8);
    PROC8(k0);
  }
#pragma unroll
  for (int j = 0; j < 8; ++j) {
    a[j] += __shfl_xor(a[j], 16, 64);
    a[j] += __shfl_xor(a[j], 32, 64);
  }
  if (grp == 0) {
    float inv = 1.f / fmaxf((float)deg[v], 1.f);
    uint4 o;
    o.x = (unsigned int)f2bf(a[0] * inv) | ((unsigned int)f2bf(a[1] * inv) << 16);
    o.y = (unsigned int)f2bf(a[2] * inv) | ((unsigned int)f2bf(a[3] * inv) << 16);
    o.z = (unsigned int)f2bf(a[4] * inv) | ((unsigned int)f2bf(a[5] * inv) << 16);
    o.w = (unsigned int)f2bf(a[6] * inv) | ((unsigned int)f2bf(a[7] * inv) << 16);
    *(uint4*)(ag + (size_t)v * D + sub * 8) = o;
  }
}

// ---------------- gemm_r: h = leaky(ag @ Wr + br), single phase, bf16 out ------------
__global__ __launch_bounds__(256) void gemm_r(const unsigned short* __restrict__ ag,
                                              const unsigned short* __restrict__ WTr,
                                              const float* __restrict__ br_,
                                              unsigned short* __restrict__ h) {
  __shared__ unsigned short wbuf[D * D];
  const int t = threadIdx.x, wave = t >> 6, lane = t & 63;
  const int l15 = lane & 15, quad = lane >> 4;
  const int base = blockIdx.x * 64 + wave * 16;
  stage_w(wbuf, WTr, t);
  bf8_t afr[4];
  load_a16(ag, base, l15, quad, afr);
  __syncthreads();
  f4_t acc[8] = {};
  tile16(wbuf, afr, l15, quad, acc);
  epi_bf<true>(acc, br_, h, base, l15, quad);
}

// ------- qk1ro1: 3-way select over {h1@Wq1->hq, h1@Wk1->hk8, out+=h1@Wro1} -----------
__global__ __launch_bounds__(256) void qk1ro1(
    const unsigned short* __restrict__ h1,
    const unsigned short* __restrict__ WTq, const float* __restrict__ bq_,
    const unsigned short* __restrict__ WTk, const float* __restrict__ bk_,
    const unsigned short* __restrict__ WTro, const float* __restrict__ bro_,
    unsigned short* __restrict__ hq, unsigned char* __restrict__ hk8,
    float* __restrict__ out) {
  __shared__ unsigned short wbuf[D * D];
  const int t = threadIdx.x, wave = t >> 6, lane = t & 63;
  const int l15 = lane & 15, quad = lane >> 4;
  const int sel = blockIdx.x;
  const int base = blockIdx.y * 64 + wave * 16;
  const unsigned short* WT = (sel == 0) ? WTq : (sel == 1) ? WTk : WTro;
  stage_w(wbuf, WT, t);
  bf8_t afr[4];
  load_a16(h1, base, l15, quad, afr);
  __syncthreads();
  f4_t acc[8] = {};
  tile16(wbuf, afr, l15, quad, acc);
  if (sel == 0) epi_bf<false>(acc, bq_, hq, base, l15, quad);
  else if (sel == 1) epi_fp8(acc, bk_, hk8, base, l15, quad);
  else epi_f32<true>(acc, bro_, out, base, l15, quad);
}

// ---------------- ro2: out += h2 @ Wro2 + bro2 ---------------------------------------
__global__ __launch_bounds__(256) void ro2(const unsigned short* __restrict__ h2,
                                           const unsigned short* __restrict__ WTro,
                                           const float* __restrict__ bro_,
                                           float* __restrict__ out) {
  __shared__ unsigned short wbuf[D * D];
  const int t = threadIdx.x, wave = t >> 6, lane = t & 63;
  const int l15 = lane & 15, quad = lane >> 4;
  const int base = blockIdx.x * 64 + wave * 16;
  stage_w(wbuf, WTro, t);
  bf8_t afr[4];
  load_a16(h2, base, l15, quad, afr);
  __syncthreads();
  f4_t acc[8] = {};
  tile16(wbuf, afr, l15, quad, acc);
  epi_f32<true>(acc, bro_, out, base, l15, quad);
}

// ---------------- launch ----------------
extern "C" void kernel_launch(void* const* d_in, const int* in_sizes, int n_in,
                              void* d_out, int out_size, void* d_ws, size_t ws_size,
                              hipStream_t stream) {
  const float* feats = (const float*)d_in[0];
  const float* Wq = (const float*)d_in[1];
  const float* bq = (const float*)d_in[2];
  const float* Wk = (const float*)d_in[3];
  const float* bk = (const float*)d_in[4];
  const float* Wr = (const float*)d_in[5];
  const float* br = (const float*)d_in[6];
  const float* Wro = (const float*)d_in[7];
  const float* bro = (const float*)d_in[8];
  const int* src = (const int*)d_in[9];
  const int* dst = (const int*)d_in[10];
  float* out = (float*)d_out;

  size_t off = 0;
  char* base = (char*)d_ws;
  auto alloc = [&](size_t bytes) -> void* {
    void* p = base + off;
    off += (bytes + 255) & ~(size_t)255;
    return p;
  };
  int* H = (int*)alloc((size_t)NB2 * NBLK1 * 4);
  int* gofs = (int*)alloc((size_t)NB2 * NBLK1 * 4);
  unsigned int* ebuf = (unsigned int*)alloc((size_t)NE * 4);
  int* ssrc = (int*)alloc((size_t)NE * 4);
  int* rowptr = (int*)alloc((size_t)(NN + 1) * 4);
  int* deg = (int*)alloc((size_t)NN * 4);
  unsigned short* WT = (unsigned short*)alloc((size_t)9 * D * D * 2);
  unsigned short* x0 = (unsigned short*)alloc((size_t)NN * D * 2);
  unsigned short* hq = (unsigned short*)alloc((size_t)NN * D * 2);
  unsigned char* hk8 = (unsigned char*)alloc((size_t)NN * D);
  unsigned short* ag = (unsigned short*)alloc((size_t)NN * D * 2);
  unsigned short* h1 = (unsigned short*)alloc((size_t)NN * D * 2);

  const size_t WM = (size_t)D * D;

  // 1: weights + feats-convert + coarse hist
  setup<<<SB_TOTAL, 256, 0, stream>>>(Wq, Wk, Wr, Wro, feats, dst, WT, x0, H);
  // 2: hierarchical offsets
  p1_scan<<<NB2, 256, 0, stream>>>(H, gofs);
  // 3: bucket scatter
  p1_scatter<<<NBLK1, 256, 0, stream>>>(src, dst, gofs, ebuf);
  // 4: per-bucket sort || QK0 GEMM || RO0 GEMM (out = x0@Wro0 + bro0)
  sort_qk0<<<NB2 + 3 * NT64, 256, 0, stream>>>(gofs, ebuf, ssrc, rowptr, deg,
                                               x0, WT + 0 * WM, bq, WT + 2 * WM, bk,
                                               WT + 6 * WM, bro, hq, hk8, out);
  // 5: aggregate L0
  aggregate<<<ABLK, 256, 0, stream>>>(rowptr, ssrc, deg, hq, hk8, ag);
  // 6: h1 = leaky(ag @ Wr0 + br0)
  gemm_r<<<NT64, 256, 0, stream>>>(ag, WT + 4 * WM, br, h1);
  // 7: hq1 / hk1(fp8) / out += h1@Wro1 — one dispatch, 3-way select
  qk1ro1<<<dim3(3, NT64), 256, 0, stream>>>(h1, WT + 1 * WM, bq + D,
                                            WT + 3 * WM, bk + D,
                                            WT + 7 * WM, bro + D, hq, hk8, out);
  // 8: aggregate L1
  aggregate<<<ABLK, 256, 0, stream>>>(rowptr, ssrc, deg, hq, hk8, ag);
  // 9: h2 = leaky(ag @ Wr1 + br1)  (reuse h1 buffer)
  gemm_r<<<NT64, 256, 0, stream>>>(ag, WT + 5 * WM, br + D, h1);
  // 10: out += h2 @ Wro2 + bro2
  ro2<<<NT64, 256, 0, stream>>>(h1, WT + 8 * WM, bro + 2 * D, out);
}